// Round 4
// baseline (171.425 us; speedup 1.0000x reference)
//
#include <hip/hip_runtime.h>
#include <math.h>

#define Tt 4096
#define Cc 1024
#define Hh 64

typedef __attribute__((ext_vector_type(8))) short bf16x8;
typedef __attribute__((ext_vector_type(4))) float f32x4;
typedef unsigned int u32;

__device__ inline unsigned short f2bf(float f) {
    unsigned u = __float_as_uint(f);
    u = (u + 0x7FFFu + ((u >> 16) & 1u)) >> 16;   // RNE
    return (unsigned short)u;
}

// async global->LDS 16B; lds base must be wave-uniform (HW: base + lane*16)
__device__ inline void gl_lds16(const unsigned short* g, unsigned short* l) {
    __builtin_amdgcn_global_load_lds(
        (const __attribute__((address_space(1))) u32*)g,
        (__attribute__((address_space(3))) u32*)l, 16, 0, 0);
}

// ---------- x fp32 -> bf16, pure streaming (max MLP) ----------
__global__ __launch_bounds__(256) void xcast(
    const float* __restrict__ x, unsigned short* __restrict__ xb)
{
    const long i = ((long)blockIdx.x * 256 + threadIdx.x) * 8;
    float4 a = *(const float4*)&x[i];
    float4 b = *(const float4*)&x[i + 4];
    ushort4 lo = { f2bf(a.x), f2bf(a.y), f2bf(a.z), f2bf(a.w) };
    ushort4 hi = { f2bf(b.x), f2bf(b.y), f2bf(b.z), f2bf(b.w) };
    *(ushort4*)&xb[i]     = lo;
    *(ushort4*)&xb[i + 4] = hi;
}

// ---------- W^T bf16 [192][1024]; kScale folded into Wq ----------
__global__ __launch_bounds__(256) void wt_build(
    const float* __restrict__ Wq, const float* __restrict__ Wk,
    const float* __restrict__ Wv, unsigned short* __restrict__ Wt)
{
    int e = blockIdx.x * 256 + threadIdx.x;   // 0..196607
    int k = e & 1023, n = e >> 10;
    float v;
    if (n < 64)       v = Wq[k * 64 + n] * 0.03125f;   // fold 1024^-0.5 into Q
    else if (n < 128) v = Wk[k * 64 + (n - 64)];
    else              v = Wv[k * 64 + (n - 128)];
    Wt[n * 1024 + k] = f2bf(v);
}

// ---------- QKV GEMM v4: async gl_lds A staging (bf16), barrier-free K-loop ----------
// 512 blocks x 4 waves, 2 blocks/CU. Block tile 32M x 192N; wave owns 32M x 48N.
// Staging: 16 async global_load_lds (16B) per thread-role -> ~256 lines in
// flight; LDS dest linear, global SOURCE pre-swizzled so LDS layout is
// row*1024 + (elem ^ ((row&7)<<3))  (identical to verified v3 read side).
// K-loop (16 steps, unrolled): 4 ds_read_b128 + 6 global b16x8 (W^T, L2) +
// 12 MFMA per wave-step; reg double-buffer on both; immediate offsets only.
__global__ __launch_bounds__(256, 2) void qkv_gemm(
    const unsigned short* __restrict__ xbf, const unsigned short* __restrict__ wt,
    unsigned short* __restrict__ qb, unsigned short* __restrict__ kb,
    unsigned short* __restrict__ vt)
{
    __shared__ unsigned short as_[32 * 1024];   // 64 KiB

    const int t = threadIdx.x, w = t >> 6, lane = t & 63;
    const int col = lane & 15, quad = lane >> 4;
    const int m0 = blockIdx.x * 32;

    // ---- stage A slab: 32 rows x 1024 K bf16, 16 async 4KB issues
    {
        const int rh = t >> 7;            // row-within-pair (wave-uniform)
        const int s  = t & 127;           // 16B segment within row
        const unsigned short* src = xbf + (long)m0 * 1024;
#pragma unroll
        for (int j = 0; j < 16; ++j) {
            int r = 2 * j + rh;
            gl_lds16(src + r * 1024 + (s ^ (r & 7)) * 8,
                     as_ + j * 2048 + w * 512);
        }
    }
    __syncthreads();   // drains gl_lds queue; the only barrier

    // ---- per-lane LDS base pointers (kc swizzle folded in)
    const unsigned short* aB[2];
#pragma unroll
    for (int kc = 0; kc < 2; ++kc)
        aB[kc] = &as_[col * 1024 + ((kc * 32 + quad * 8) ^ ((col & 7) << 3))];
    // reads: aB[kc] + mt*16*1024 + k*64   (pure immediates)

    // ---- B base pointers: wave w owns n-tiles w*3 .. w*3+2
    const unsigned short* pB[3];
#pragma unroll
    for (int nt = 0; nt < 3; ++nt)
        pB[nt] = wt + ((w * 3 + nt) * 16 + col) * 1024 + quad * 8;
    // reads: pB[nt] + k*64 + kc*32   (pure immediates)

    f32x4 acc[2][3];
#pragma unroll
    for (int mt = 0; mt < 2; ++mt)
#pragma unroll
        for (int nt = 0; nt < 3; ++nt) acc[mt][nt] = (f32x4){0.f, 0.f, 0.f, 0.f};

    bf16x8 bfr[2][3][2];   // [buf][nt][kc]
    bf16x8 afr[2][2][2];   // [buf][mt][kc]

    // prologue loads for k = 0
#pragma unroll
    for (int nt = 0; nt < 3; ++nt)
#pragma unroll
        for (int kc = 0; kc < 2; ++kc)
            bfr[0][nt][kc] = *(const bf16x8*)(pB[nt] + kc * 32);
#pragma unroll
    for (int mt = 0; mt < 2; ++mt)
#pragma unroll
        for (int kc = 0; kc < 2; ++kc)
            afr[0][mt][kc] = *(const bf16x8*)(aB[kc] + mt * 16 * 1024);

#pragma unroll
    for (int k = 0; k < 16; ++k) {
        const int cur = k & 1, nxt = cur ^ 1;
        if (k < 15) {
            const int ko = (k + 1) * 64;
#pragma unroll
            for (int nt = 0; nt < 3; ++nt)
#pragma unroll
                for (int kc = 0; kc < 2; ++kc)
                    bfr[nxt][nt][kc] = *(const bf16x8*)(pB[nt] + ko + kc * 32);
#pragma unroll
            for (int mt = 0; mt < 2; ++mt)
#pragma unroll
                for (int kc = 0; kc < 2; ++kc)
                    afr[nxt][mt][kc] = *(const bf16x8*)(aB[kc] + mt * 16 * 1024 + ko);
        }
#pragma unroll
        for (int kc = 0; kc < 2; ++kc)
#pragma unroll
            for (int nt = 0; nt < 3; ++nt)
#pragma unroll
                for (int mt = 0; mt < 2; ++mt)
                    acc[mt][nt] = __builtin_amdgcn_mfma_f32_16x16x32_bf16(
                        afr[cur][mt][kc], bfr[cur][nt][kc], acc[mt][nt], 0, 0, 0);
    }

    // ---- epilogue: wave w -> n-tiles ntg = 3w..3w+2, rows m0 + mt*16 + quad*4 + reg
    const long bidx = m0 >> 12;
    const int tbase = m0 & 4095;
#pragma unroll
    for (int mt = 0; mt < 2; ++mt)
#pragma unroll
        for (int nt = 0; nt < 3; ++nt) {
            int ntg = w * 3 + nt;
            int n = ntg * 16 + col;
            int row = m0 + mt * 16 + quad * 4;
            if (ntg < 4) {
#pragma unroll
                for (int reg = 0; reg < 4; ++reg)
                    qb[(long)(row + reg) * Hh + n] = f2bf(acc[mt][nt][reg]);
            } else if (ntg < 8) {
#pragma unroll
                for (int reg = 0; reg < 4; ++reg)
                    kb[(long)(row + reg) * Hh + (n - 64)] = f2bf(acc[mt][nt][reg]);
            } else {
                int h = n - 128;
                ushort4 pk = { f2bf(acc[mt][nt][0]), f2bf(acc[mt][nt][1]),
                               f2bf(acc[mt][nt][2]), f2bf(acc[mt][nt][3]) };
                *(ushort4*)&vt[(bidx * Hh + h) * (long)Tt + tbase + mt * 16 + quad * 4] = pk;
            }
        }
}

// ---------- flash attention: static-max softmax, barrier-free K-loop ----------
// LDS: pl aliased into this wave's own o_red slice (o_red written only after
// the wave's last pl read) -> 34.5 KB total -> 4 blocks/CU.
#define LDP 56
#define LDO 68

__global__ __launch_bounds__(256) void attn(
    const unsigned short* __restrict__ qg, const unsigned short* __restrict__ kg,
    const unsigned short* __restrict__ vtg,
    float* __restrict__ po, float* __restrict__ pls)
{
    __shared__ __align__(16) char smem[35328];
    float* o_red       = (float*)smem;                      // 34816 B
    float* lred        = (float*)(smem + 34816);            // 512 B
    unsigned short* pl = (unsigned short*)smem;             // per-wave slice below

    const int p    = blockIdx.x;
    const int qt   = 127 - (p >> 3);
    const int b    = p & 3;
    const int half = (p >> 2) & 1;
    const int tid  = (b << 7) | qt;
    const long qrow0 = (long)b * Tt + qt * 32;
    const int nkt = qt + 1;
    const int n0  = (nkt + 1) >> 1;
    const int cnt = half ? (nkt - n0) : n0;
    const int ust = half ? n0 : 0;

    const int t = threadIdx.x, w = t >> 6, lane = t & 63;
    const int col = lane & 15, quad = lane >> 4;
    const int plbase = w * 4352;   // shorts: wave w's own 8704B o_red slice

    bf16x8 qf[2][2];
#pragma unroll
    for (int mt = 0; mt < 2; ++mt)
#pragma unroll
        for (int kc = 0; kc < 2; ++kc)
            qf[mt][kc] = *(const bf16x8*)&qg[(qrow0 + mt * 16 + col) * Hh + kc * 32 + quad * 8];

    f32x4 oacc[2][4];
#pragma unroll
    for (int mt = 0; mt < 2; ++mt)
#pragma unroll
        for (int nt = 0; nt < 4; ++nt) oacc[mt][nt] = (f32x4){0.f, 0.f, 0.f, 0.f};
    float lsum[2][4] = {{0.f,0.f,0.f,0.f},{0.f,0.f,0.f,0.f}};

    for (int iu = w; iu < cnt; iu += 4) {
        const int u = ust + iu;
        const long krow0 = (long)b * Tt + u * 32;
        bf16x8 kf[2][2];
#pragma unroll
        for (int nt = 0; nt < 2; ++nt)
#pragma unroll
            for (int kc = 0; kc < 2; ++kc)
                kf[nt][kc] = *(const bf16x8*)&kg[(krow0 + nt * 16 + col) * Hh + kc * 32 + quad * 8];
        f32x4 s[2][2];
#pragma unroll
        for (int mt = 0; mt < 2; ++mt)
#pragma unroll
            for (int nt = 0; nt < 2; ++nt) {
                s[mt][nt] = (f32x4){0.f, 0.f, 0.f, 0.f};
#pragma unroll
                for (int kc = 0; kc < 2; ++kc)
                    s[mt][nt] = __builtin_amdgcn_mfma_f32_16x16x32_bf16(qf[mt][kc], kf[nt][kc], s[mt][nt], 0, 0, 0);
            }
#pragma unroll
        for (int mt = 0; mt < 2; ++mt)
#pragma unroll
            for (int reg = 0; reg < 4; ++reg) {
                int rloc = mt * 16 + quad * 4 + reg;
                if (u == qt) {
                    if (col > rloc)      s[mt][0][reg] = -INFINITY;
                    if (16 + col > rloc) s[mt][1][reg] = -INFINITY;
                }
                float p0 = __expf(s[mt][0][reg]);
                float p1 = __expf(s[mt][1][reg]);
                lsum[mt][reg] += p0 + p1;
                pl[plbase + rloc * LDP + col]      = f2bf(p0);
                pl[plbase + rloc * LDP + 16 + col] = f2bf(p1);
            }
        bf16x8 af0 = *(const bf16x8*)&pl[plbase + col * LDP + quad * 8];
        bf16x8 af1 = *(const bf16x8*)&pl[plbase + (16 + col) * LDP + quad * 8];
#pragma unroll
        for (int nt = 0; nt < 4; ++nt) {
            bf16x8 vf = *(const bf16x8*)&vtg[((long)b * Hh + nt * 16 + col) * Tt + u * 32 + quad * 8];
            oacc[0][nt] = __builtin_amdgcn_mfma_f32_16x16x32_bf16(af0, vf, oacc[0][nt], 0, 0, 0);
            oacc[1][nt] = __builtin_amdgcn_mfma_f32_16x16x32_bf16(af1, vf, oacc[1][nt], 0, 0, 0);
        }
    }

#pragma unroll
    for (int mt = 0; mt < 2; ++mt)
#pragma unroll
        for (int reg = 0; reg < 4; ++reg) {
            float l = lsum[mt][reg];
            l += __shfl_xor(l, 1); l += __shfl_xor(l, 2);
            l += __shfl_xor(l, 4); l += __shfl_xor(l, 8);
            if (col == 0) lred[w * 32 + mt * 16 + quad * 4 + reg] = l;
        }
    // wave w's o_red slice = rows [w*32, w*32+32) -- overwrites its own pl
#pragma unroll
    for (int mt = 0; mt < 2; ++mt)
#pragma unroll
        for (int nt = 0; nt < 4; ++nt)
#pragma unroll
            for (int reg = 0; reg < 4; ++reg)
                o_red[(w * 32 + mt * 16 + quad * 4 + reg) * LDO + nt * 16 + col] = oacc[mt][nt][reg];
    __syncthreads();
    if (t < 32)
        pls[(tid * 2 + half) * 32 + t] = lred[t] + lred[32 + t] + lred[64 + t] + lred[96 + t];
    float* pob = po + ((long)tid * 2 + half) * 2048;
#pragma unroll
    for (int j = 0; j < 8; ++j) {
        int e = t + 256 * j, r = e >> 6, c = e & 63;
        pob[e] = o_red[r * LDO + c] + o_red[(32 + r) * LDO + c]
               + o_red[(64 + r) * LDO + c] + o_red[(96 + r) * LDO + c];
    }
}

// ---------- combine: out = (O0+O1)/(l0+l1) ----------
__global__ __launch_bounds__(256) void combine(
    const float* __restrict__ po, const float* __restrict__ pls, float* __restrict__ out)
{
    const int g = blockIdx.x;
    const long orow = (((long)(g >> 7)) * Tt + (long)(g & 127) * 32) * Hh;
    const float* p0 = po + (long)g * 2 * 2048;
    const float* p1 = p0 + 2048;
    const float* l0 = pls + g * 2 * 32;
    const float* l1 = l0 + 32;
    const int t = threadIdx.x;
#pragma unroll
    for (int j = 0; j < 8; ++j) {
        int e = t + 256 * j, r = e >> 6;
        out[orow + e] = (p0[e] + p1[e]) / (l0[r] + l1[r]);
    }
}

extern "C" void kernel_launch(void* const* d_in, const int* in_sizes, int n_in,
                              void* d_out, int out_size, void* d_ws, size_t ws_size,
                              hipStream_t stream)
{
    const float* x  = (const float*)d_in[0];
    const float* Wq = (const float*)d_in[1];
    const float* Wk = (const float*)d_in[2];
    const float* Wv = (const float*)d_in[3];
    float* outp = (float*)d_out;

    unsigned short* wt = (unsigned short*)d_ws;       // 192*1024 bf16 (384 KB)
    unsigned short* qb = wt + 196608;                 // 2 MB
    unsigned short* kb = qb + 1048576;                // 2 MB
    unsigned short* vt = kb + 1048576;                // V^T [b][h][t] (2 MB)
    float* po  = (float*)(vt + 1048576);              // [512][2][2048] (8 MB)
    float* pls = po + 2097152;                        // [512][2][32] (128 KB)
    unsigned short* xbf = (unsigned short*)(pls + 32768);  // x in bf16 (33.5 MB)

    xcast   <<<dim3(8192), dim3(256), 0, stream>>>(x, xbf);
    wt_build<<<dim3(768),  dim3(256), 0, stream>>>(Wq, Wk, Wv, wt);
    qkv_gemm<<<dim3(512),  dim3(256), 0, stream>>>(xbf, wt, qb, kb, vt);
    attn    <<<dim3(1024), dim3(256), 0, stream>>>(qb, kb, vt, po, pls);
    combine <<<dim3(512),  dim3(256), 0, stream>>>(po, pls, outp);
}

// Round 5
// 161.425 us; speedup vs baseline: 1.0619x; 1.0619x over previous
//
#include <hip/hip_runtime.h>
#include <math.h>

#define Tt 4096
#define Cc 1024
#define Hh 64

typedef __attribute__((ext_vector_type(8))) short bf16x8;
typedef __attribute__((ext_vector_type(4))) float f32x4;
typedef unsigned int u32;

__device__ inline unsigned short f2bf(float f) {
    unsigned u = __float_as_uint(f);
    u = (u + 0x7FFFu + ((u >> 16) & 1u)) >> 16;   // RNE
    return (unsigned short)u;
}

// ---------- W^T bf16 [192][1024]; kScale folded into Wq ----------
__global__ __launch_bounds__(256) void wt_build(
    const float* __restrict__ Wq, const float* __restrict__ Wk,
    const float* __restrict__ Wv, unsigned short* __restrict__ Wt)
{
    int e = blockIdx.x * 256 + threadIdx.x;   // 0..196607
    int k = e & 1023, n = e >> 10;
    float v;
    if (n < 64)       v = Wq[k * 64 + n] * 0.03125f;   // fold 1024^-0.5 into Q
    else if (n < 128) v = Wk[k * 64 + (n - 64)];
    else              v = Wv[k * 64 + (n - 128)];
    Wt[n * 1024 + k] = f2bf(v);
}

// ---------- QKV GEMM v5: direct fp32 x, batched-MLP staging, barrier-free K-loop ----------
// 512 blocks x 4 waves, 2 blocks/CU (64KB LDS). Block 32M x 192N; wave 32M x 48N.
// Staging (T14 issue-early/write-late): 2 groups of 16 INDEPENDENT float4 loads
// into regs, then convert+swizzled-LDS-write. ~512 HBM lines in flight per CU
// (vs ~30 for the v3 load->convert->write chain). x is read exactly once.
// K-loop (16 steps, unrolled): 4 ds_read_b128 + 6 global b16x8 (W^T, L2) +
// 12 MFMA per wave-step; reg double-buffer on both; immediate offsets only.
// LDS layout: row*1024 + (elem ^ ((row&7)<<3))  (identical to verified v3).
__global__ __launch_bounds__(256, 2) void qkv_gemm(
    const float* __restrict__ x, const unsigned short* __restrict__ wt,
    unsigned short* __restrict__ qb, unsigned short* __restrict__ kb,
    unsigned short* __restrict__ vt)
{
    __shared__ unsigned short as_[32 * 1024];   // 64 KiB

    const int t = threadIdx.x, w = t >> 6, lane = t & 63;
    const int col = lane & 15, quad = lane >> 4;
    const int m0 = blockIdx.x * 32;

    // ---- stage A slab: 32 rows x 1024 K fp32 -> bf16 LDS, batched loads
    {
        const float* xb = x + (long)m0 * Cc;
        float4 vbuf[16];
#pragma unroll
        for (int g = 0; g < 2; ++g) {
#pragma unroll
            for (int s = 0; s < 16; ++s) {          // 16 independent loads
                int row = g * 16 + s;
                vbuf[s] = *(const float4*)&xb[row * 1024 + t * 4];
            }
#pragma unroll
            for (int s = 0; s < 16; ++s) {          // convert + swizzled write
                int row = g * 16 + s;
                ushort4 pk = { f2bf(vbuf[s].x), f2bf(vbuf[s].y),
                               f2bf(vbuf[s].z), f2bf(vbuf[s].w) };
                int woff = (t * 4) ^ ((row & 7) << 3);
                *(ushort4*)&as_[row * 1024 + woff] = pk;
            }
        }
    }
    __syncthreads();   // the only barrier

    // ---- per-lane LDS base pointers (kc swizzle folded in)
    const unsigned short* aB[2];
#pragma unroll
    for (int kc = 0; kc < 2; ++kc)
        aB[kc] = &as_[col * 1024 + ((kc * 32 + quad * 8) ^ ((col & 7) << 3))];
    // reads: aB[kc] + mt*16*1024 + k*64   (pure immediates)

    // ---- B base pointers: wave w owns n-tiles w*3 .. w*3+2
    const unsigned short* pB[3];
#pragma unroll
    for (int nt = 0; nt < 3; ++nt)
        pB[nt] = wt + ((w * 3 + nt) * 16 + col) * 1024 + quad * 8;
    // reads: pB[nt] + k*64 + kc*32   (pure immediates)

    f32x4 acc[2][3];
#pragma unroll
    for (int mt = 0; mt < 2; ++mt)
#pragma unroll
        for (int nt = 0; nt < 3; ++nt) acc[mt][nt] = (f32x4){0.f, 0.f, 0.f, 0.f};

    bf16x8 bfr[2][3][2];   // [buf][nt][kc]
    bf16x8 afr[2][2][2];   // [buf][mt][kc]

    // prologue loads for k = 0
#pragma unroll
    for (int nt = 0; nt < 3; ++nt)
#pragma unroll
        for (int kc = 0; kc < 2; ++kc)
            bfr[0][nt][kc] = *(const bf16x8*)(pB[nt] + kc * 32);
#pragma unroll
    for (int mt = 0; mt < 2; ++mt)
#pragma unroll
        for (int kc = 0; kc < 2; ++kc)
            afr[0][mt][kc] = *(const bf16x8*)(aB[kc] + mt * 16 * 1024);

#pragma unroll
    for (int k = 0; k < 16; ++k) {
        const int cur = k & 1, nxt = cur ^ 1;
        if (k < 15) {
            const int ko = (k + 1) * 64;
#pragma unroll
            for (int nt = 0; nt < 3; ++nt)
#pragma unroll
                for (int kc = 0; kc < 2; ++kc)
                    bfr[nxt][nt][kc] = *(const bf16x8*)(pB[nt] + ko + kc * 32);
#pragma unroll
            for (int mt = 0; mt < 2; ++mt)
#pragma unroll
                for (int kc = 0; kc < 2; ++kc)
                    afr[nxt][mt][kc] = *(const bf16x8*)(aB[kc] + mt * 16 * 1024 + ko);
        }
#pragma unroll
        for (int kc = 0; kc < 2; ++kc)
#pragma unroll
            for (int nt = 0; nt < 3; ++nt)
#pragma unroll
                for (int mt = 0; mt < 2; ++mt)
                    acc[mt][nt] = __builtin_amdgcn_mfma_f32_16x16x32_bf16(
                        afr[cur][mt][kc], bfr[cur][nt][kc], acc[mt][nt], 0, 0, 0);
    }

    // ---- epilogue: wave w -> n-tiles ntg = 3w..3w+2, rows m0 + mt*16 + quad*4 + reg
    const long bidx = m0 >> 12;
    const int tbase = m0 & 4095;
#pragma unroll
    for (int mt = 0; mt < 2; ++mt)
#pragma unroll
        for (int nt = 0; nt < 3; ++nt) {
            int ntg = w * 3 + nt;
            int n = ntg * 16 + col;
            int row = m0 + mt * 16 + quad * 4;
            if (ntg < 4) {
#pragma unroll
                for (int reg = 0; reg < 4; ++reg)
                    qb[(long)(row + reg) * Hh + n] = f2bf(acc[mt][nt][reg]);
            } else if (ntg < 8) {
#pragma unroll
                for (int reg = 0; reg < 4; ++reg)
                    kb[(long)(row + reg) * Hh + (n - 64)] = f2bf(acc[mt][nt][reg]);
            } else {
                int h = n - 128;
                ushort4 pk = { f2bf(acc[mt][nt][0]), f2bf(acc[mt][nt][1]),
                               f2bf(acc[mt][nt][2]), f2bf(acc[mt][nt][3]) };
                *(ushort4*)&vt[(bidx * Hh + h) * (long)Tt + tbase + mt * 16 + quad * 4] = pk;
            }
        }
}

// ---------- flash attention v3: 2-deep K/V reg prefetch + setprio ----------
// LDS: pl aliased into this wave's own o_red slice -> 34.5 KB, 4 blocks/CU.
#define LDP 56
#define LDO 68

__global__ __launch_bounds__(256) void attn(
    const unsigned short* __restrict__ qg, const unsigned short* __restrict__ kg,
    const unsigned short* __restrict__ vtg,
    float* __restrict__ po, float* __restrict__ pls)
{
    __shared__ __align__(16) char smem[35328];
    float* o_red       = (float*)smem;                      // 34816 B
    float* lred        = (float*)(smem + 34816);            // 512 B
    unsigned short* pl = (unsigned short*)smem;             // per-wave slice

    const int p    = blockIdx.x;
    const int qt   = 127 - (p >> 3);
    const int b    = p & 3;
    const int half = (p >> 2) & 1;
    const int tid  = (b << 7) | qt;
    const long qrow0 = (long)b * Tt + qt * 32;
    const int nkt = qt + 1;
    const int n0  = (nkt + 1) >> 1;
    const int cnt = half ? (nkt - n0) : n0;
    const int ust = half ? n0 : 0;

    const int t = threadIdx.x, w = t >> 6, lane = t & 63;
    const int col = lane & 15, quad = lane >> 4;
    const int plbase = w * 4352;   // shorts: wave w's own 8704B o_red slice

    bf16x8 qf[2][2];
#pragma unroll
    for (int mt = 0; mt < 2; ++mt)
#pragma unroll
        for (int kc = 0; kc < 2; ++kc)
            qf[mt][kc] = *(const bf16x8*)&qg[(qrow0 + mt * 16 + col) * Hh + kc * 32 + quad * 8];

    f32x4 oacc[2][4];
#pragma unroll
    for (int mt = 0; mt < 2; ++mt)
#pragma unroll
        for (int nt = 0; nt < 4; ++nt) oacc[mt][nt] = (f32x4){0.f, 0.f, 0.f, 0.f};
    float lsum[2][4] = {{0.f,0.f,0.f,0.f},{0.f,0.f,0.f,0.f}};

    auto loadK = [&](bf16x8 (&kf)[2][2], int iu_) {
        const long krow0 = (long)b * Tt + (ust + iu_) * 32;
#pragma unroll
        for (int nt = 0; nt < 2; ++nt)
#pragma unroll
            for (int kc = 0; kc < 2; ++kc)
                kf[nt][kc] = *(const bf16x8*)&kg[(krow0 + nt * 16 + col) * Hh + kc * 32 + quad * 8];
    };
    auto loadV = [&](bf16x8 (&vf)[4], int iu_) {
        const int u = ust + iu_;
#pragma unroll
        for (int nt = 0; nt < 4; ++nt)
            vf[nt] = *(const bf16x8*)&vtg[((long)b * Hh + nt * 16 + col) * Tt + u * 32 + quad * 8];
    };
    auto compute = [&](bf16x8 (&kf)[2][2], bf16x8 (&vf)[4], int u) {
        f32x4 s[2][2];
        __builtin_amdgcn_s_setprio(1);
#pragma unroll
        for (int mt = 0; mt < 2; ++mt)
#pragma unroll
            for (int nt = 0; nt < 2; ++nt) {
                s[mt][nt] = (f32x4){0.f, 0.f, 0.f, 0.f};
#pragma unroll
                for (int kc = 0; kc < 2; ++kc)
                    s[mt][nt] = __builtin_amdgcn_mfma_f32_16x16x32_bf16(
                        qf[mt][kc], kf[nt][kc], s[mt][nt], 0, 0, 0);
            }
        __builtin_amdgcn_s_setprio(0);
#pragma unroll
        for (int mt = 0; mt < 2; ++mt)
#pragma unroll
            for (int reg = 0; reg < 4; ++reg) {
                int rloc = mt * 16 + quad * 4 + reg;
                if (u == qt) {
                    if (col > rloc)      s[mt][0][reg] = -INFINITY;
                    if (16 + col > rloc) s[mt][1][reg] = -INFINITY;
                }
                float p0 = __expf(s[mt][0][reg]);
                float p1 = __expf(s[mt][1][reg]);
                lsum[mt][reg] += p0 + p1;
                pl[plbase + rloc * LDP + col]      = f2bf(p0);
                pl[plbase + rloc * LDP + 16 + col] = f2bf(p1);
            }
        bf16x8 af0 = *(const bf16x8*)&pl[plbase + col * LDP + quad * 8];
        bf16x8 af1 = *(const bf16x8*)&pl[plbase + (16 + col) * LDP + quad * 8];
        __builtin_amdgcn_s_setprio(1);
#pragma unroll
        for (int nt = 0; nt < 4; ++nt) {
            oacc[0][nt] = __builtin_amdgcn_mfma_f32_16x16x32_bf16(af0, vf[nt], oacc[0][nt], 0, 0, 0);
            oacc[1][nt] = __builtin_amdgcn_mfma_f32_16x16x32_bf16(af1, vf[nt], oacc[1][nt], 0, 0, 0);
        }
        __builtin_amdgcn_s_setprio(0);
    };

    // 2-deep software pipeline with static A/B buffers (no runtime indexing)
    bf16x8 kA[2][2], vA[4], kB[2][2], vB[4];
    int iu = w;
    if (iu < cnt) { loadK(kA, iu); loadV(vA, iu); }
    while (iu < cnt) {
        int i1 = iu + 4;
        if (i1 < cnt) { loadK(kB, i1); loadV(vB, i1); }   // in flight under A
        compute(kA, vA, ust + iu);
        if (i1 >= cnt) break;
        int i2 = i1 + 4;
        if (i2 < cnt) { loadK(kA, i2); loadV(vA, i2); }   // in flight under B
        compute(kB, vB, ust + i1);
        iu = i2;
    }

#pragma unroll
    for (int mt = 0; mt < 2; ++mt)
#pragma unroll
        for (int reg = 0; reg < 4; ++reg) {
            float l = lsum[mt][reg];
            l += __shfl_xor(l, 1); l += __shfl_xor(l, 2);
            l += __shfl_xor(l, 4); l += __shfl_xor(l, 8);
            if (col == 0) lred[w * 32 + mt * 16 + quad * 4 + reg] = l;
        }
    // wave w's o_red slice = rows [w*32, w*32+32) -- overwrites its own pl
#pragma unroll
    for (int mt = 0; mt < 2; ++mt)
#pragma unroll
        for (int nt = 0; nt < 4; ++nt)
#pragma unroll
            for (int reg = 0; reg < 4; ++reg)
                o_red[(w * 32 + mt * 16 + quad * 4 + reg) * LDO + nt * 16 + col] = oacc[mt][nt][reg];
    __syncthreads();
    if (t < 32)
        pls[(tid * 2 + half) * 32 + t] = lred[t] + lred[32 + t] + lred[64 + t] + lred[96 + t];
    float* pob = po + ((long)tid * 2 + half) * 2048;
#pragma unroll
    for (int j = 0; j < 8; ++j) {
        int e = t + 256 * j, r = e >> 6, c = e & 63;
        pob[e] = o_red[r * LDO + c] + o_red[(32 + r) * LDO + c]
               + o_red[(64 + r) * LDO + c] + o_red[(96 + r) * LDO + c];
    }
}

// ---------- combine: out = (O0+O1)/(l0+l1) ----------
__global__ __launch_bounds__(256) void combine(
    const float* __restrict__ po, const float* __restrict__ pls, float* __restrict__ out)
{
    const int g = blockIdx.x;
    const long orow = (((long)(g >> 7)) * Tt + (long)(g & 127) * 32) * Hh;
    const float* p0 = po + (long)g * 2 * 2048;
    const float* p1 = p0 + 2048;
    const float* l0 = pls + g * 2 * 32;
    const float* l1 = l0 + 32;
    const int t = threadIdx.x;
#pragma unroll
    for (int j = 0; j < 8; ++j) {
        int e = t + 256 * j, r = e >> 6;
        out[orow + e] = (p0[e] + p1[e]) / (l0[r] + l1[r]);
    }
}

extern "C" void kernel_launch(void* const* d_in, const int* in_sizes, int n_in,
                              void* d_out, int out_size, void* d_ws, size_t ws_size,
                              hipStream_t stream)
{
    const float* x  = (const float*)d_in[0];
    const float* Wq = (const float*)d_in[1];
    const float* Wk = (const float*)d_in[2];
    const float* Wv = (const float*)d_in[3];
    float* outp = (float*)d_out;

    unsigned short* wt = (unsigned short*)d_ws;       // 192*1024 bf16 (384 KB)
    unsigned short* qb = wt + 196608;                 // 2 MB
    unsigned short* kb = qb + 1048576;                // 2 MB
    unsigned short* vt = kb + 1048576;                // V^T [b][h][t] (2 MB)
    float* po  = (float*)(vt + 1048576);              // [512][2][2048] (8 MB)
    float* pls = po + 2097152;                        // [512][2][32]

    wt_build<<<dim3(768), dim3(256), 0, stream>>>(Wq, Wk, Wv, wt);
    qkv_gemm<<<dim3(512), dim3(256), 0, stream>>>(x, wt, qb, kb, vt);
    attn<<<dim3(1024), dim3(256), 0, stream>>>(qb, kb, vt, po, pls);
    combine<<<dim3(512), dim3(256), 0, stream>>>(po, pls, outp);
}